// Round 1
// baseline (414.003 us; speedup 1.0000x reference)
//
#include <hip/hip_runtime.h>
#include <math.h>

// Problem: N=262144 samples, D=128, C=1024. fp32 embeddings, int64/int32 labels.
// Identity: per_class = (count - ||sum_{i in c} norm(emb_i)||) / count.
// Strategy: NO sort/gather. Streaming passes + LDS-privatized segment sums.
#define NUM_CLASSES 1024
#define CHUNK 4096                 // samples per accum block

__device__ __forceinline__ int detect_mode32(const int* __restrict__ l) {
    // 1 -> labels are int32, 0 -> int64 (read low words). Uniform scalar loads.
    return (l[1] | l[3] | l[5] | l[7] | l[9] | l[11] | l[13] | l[15]) != 0;
}

__device__ __forceinline__ int get_label(const int* __restrict__ l, int i, int mode32) {
    return l[mode32 ? i : (i << 1)] & (NUM_CLASSES - 1);
}

// ---------------- K1: inv-norm per sample + global class histogram ----------------
// grid = ceil(n/128) blocks x 256 thr. 32 lanes per row (float4 each = 512 B row),
// 4 waves x 2 half-waves = 8 rows/iter, 16 iters. Fully coalesced streaming.
__global__ __launch_bounds__(256) void norm_hist_kernel(
        const float* __restrict__ emb, const int* __restrict__ labels, int n,
        float* __restrict__ inv_norm, int* __restrict__ counts) {
    __shared__ int hist[NUM_CLASSES];
    const int mode32 = detect_mode32(labels);
    for (int c = threadIdx.x; c < NUM_CLASSES; c += 256) hist[c] = 0;
    __syncthreads();
    const int wave = threadIdx.x >> 6;
    const int lane = threadIdx.x & 63;
    const int half = lane >> 5;           // half-wave 0/1
    const int l32  = lane & 31;           // lane within row
    const float4* emb4 = (const float4*)emb;
    const int base = blockIdx.x * 128;
    #pragma unroll 4
    for (int it = 0; it < 16; ++it) {
        int r = base + it * 8 + wave * 2 + half;
        if (r < n) {
            float4 v = emb4[(size_t)r * 32 + l32];
            float sq = v.x*v.x + v.y*v.y + v.z*v.z + v.w*v.w;
            sq += __shfl_xor(sq, 1, 64);
            sq += __shfl_xor(sq, 2, 64);
            sq += __shfl_xor(sq, 4, 64);
            sq += __shfl_xor(sq, 8, 64);
            sq += __shfl_xor(sq, 16, 64);   // masks <=16 stay within the 32-lane half
            if (l32 == 0) {
                inv_norm[r] = 1.0f / fmaxf(sqrtf(sq), 1e-12f);
                atomicAdd(&hist[get_label(labels, r, mode32)], 1);
            }
        }
    }
    __syncthreads();
    for (int c = threadIdx.x; c < NUM_CLASSES; c += 256) {
        int h = hist[c];
        if (h) atomicAdd(&counts[c], h);
    }
}

// ---------------- K2: dim/class-split segment-sum accumulation ----------------
// blockIdx.x: dg = bx&3 (32-dim slice), half = (bx>>2)&1 (512-class half),
// chunk = bx>>3 (4096-sample range). LDS [512][32] f32 = 64 KB, XOR-swizzled so
// ds_add_f32 bank = (4j+k)^label -> spread across 32 banks per wave.
// Each 128-B dim-slice of each row is read exactly once device-wide, coalesced.
__global__ __launch_bounds__(1024) void accum_kernel(
        const float* __restrict__ emb, const int* __restrict__ labels, int n,
        const float* __restrict__ inv_norm, float* __restrict__ sums) {
    __shared__ float lds[512 * 32];       // 64 KB -> 2 blocks/CU, 32 waves/CU
    const int mode32 = detect_mode32(labels);
    const int dg    = blockIdx.x & 3;
    const int half  = (blockIdx.x >> 2) & 1;
    const int chunk = blockIdx.x >> 3;
    for (int t = threadIdx.x; t < 512 * 32; t += 1024) lds[t] = 0.0f;
    __syncthreads();
    const int wave = threadIdx.x >> 6;
    const int lane = threadIdx.x & 63;
    const int sj   = lane >> 3;           // sample slot 0..7 within wave
    const int j    = lane & 7;            // float4 slot within 32-dim slice
    const float4* emb4 = (const float4*)emb;
    const int base = chunk * CHUNK;
    for (int it = 0; it < CHUNK / 128; ++it) {      // 32 iters
        int i = base + it * 128 + wave * 8 + sj;
        if (i < n) {
            int lab = get_label(labels, i, mode32);
            if ((lab >> 9) == half) {
                float inv = inv_norm[i];
                float4 v = emb4[(size_t)i * 32 + dg * 8 + j];
                int cl = lab & 511;
                int sw = lab & 31;
                float* row = &lds[cl << 5];
                int o = j << 2;           // dims dg*32 + 4j + k
                atomicAdd(&row[(o + 0) ^ sw], v.x * inv);
                atomicAdd(&row[(o + 1) ^ sw], v.y * inv);
                atomicAdd(&row[(o + 2) ^ sw], v.z * inv);
                atomicAdd(&row[(o + 3) ^ sw], v.w * inv);
            }
        }
    }
    __syncthreads();
    // Flush: un-swizzle and add into global sums[1024][128] with HW f32 atomics.
    for (int t = threadIdx.x; t < 512 * 32; t += 1024) {
        int cl = t >> 5, p = t & 31;
        int jd = p ^ (cl & 31);           // stored pos -> dim offset
        unsafeAtomicAdd(&sums[(size_t)(half * 512 + cl) * 128 + dg * 32 + jd], lds[t]);
    }
}

// ---------------- K3: per-class norm -> loss, ticket finalize ----------------
// 64 blocks x 256 thr, 16 classes per block, 16 lanes per class row.
__global__ __launch_bounds__(256) void finalize_kernel(
        const float* __restrict__ sums, const int* __restrict__ counts,
        float* __restrict__ accum, int* __restrict__ ticket,
        float* __restrict__ out) {
    const int wave = threadIdx.x >> 6;
    const int lane = threadIdx.x & 63;
    const int g    = lane >> 4;
    const int sub  = lane & 15;
    const int c    = blockIdx.x * 16 + wave * 4 + g;
    const float4* s4 = (const float4*)sums;
    float4 a = s4[(size_t)c * 32 + sub];
    float4 b = s4[(size_t)c * 32 + 16 + sub];
    float sq = a.x*a.x + a.y*a.y + a.z*a.z + a.w*a.w
             + b.x*b.x + b.y*b.y + b.z*b.z + b.w*b.w;
    sq += __shfl_xor(sq, 1, 64);
    sq += __shfl_xor(sq, 2, 64);
    sq += __shfl_xor(sq, 4, 64);
    sq += __shfl_xor(sq, 8, 64);
    if (sub == 0) {
        int count = counts[c];
        if (count >= 2) {
            float per_class = ((float)count - sqrtf(sq)) / (float)count;
            atomicAdd(&accum[0], per_class);
            atomicAdd(&accum[1], 1.0f);
        }
    }
    __syncthreads();
    if (threadIdx.x == 0) {
        __threadfence();
        int old = atomicAdd(ticket, 1);
        if (old == (int)gridDim.x - 1) {
            float ls = atomicAdd(&accum[0], 0.0f);   // device-scope atomic reads
            float nv = atomicAdd(&accum[1], 0.0f);
            out[0] = (nv > 0.0f) ? (ls / nv) : 0.0f;
        }
    }
}

extern "C" void kernel_launch(void* const* d_in, const int* in_sizes, int n_in,
                              void* d_out, int out_size, void* d_ws, size_t ws_size,
                              hipStream_t stream) {
    const float* emb  = (const float*)d_in[0];   // fp32, N x 128
    const int* labels = (const int*)d_in[1];     // int32 (int64 handled inline)
    const int n = in_sizes[1];                   // 262144 samples

    // Workspace layout (~1.55 MB)
    char* ws = (char*)d_ws;
    float* sums     = (float*)(ws);              // 1024*128 f32 = 512 KB
    int*   counts   = (int*)(ws + 524288);       // 1024 ints
    float* accum    = (float*)(ws + 528384);     // 2 floats
    int*   ticket   = (int*)(ws + 528392);       // 1 int
    float* inv_norm = (float*)(ws + 528640);     // n floats (1 MB)

    hipMemsetAsync(ws, 0, 528640, stream);       // zero sums/counts/accum/ticket

    int nb1 = (n + 127) / 128;                   // 2048 blocks
    norm_hist_kernel<<<nb1, 256, 0, stream>>>(emb, labels, n, inv_norm, counts);

    int chunks = (n + CHUNK - 1) / CHUNK;        // 64 chunks
    accum_kernel<<<chunks * 8, 1024, 0, stream>>>(emb, labels, n, inv_norm, sums);

    finalize_kernel<<<64, 256, 0, stream>>>(sums, counts, accum, ticket,
                                            (float*)d_out);
}

// Round 2
// 249.544 us; speedup vs baseline: 1.6590x; 1.6590x over previous
//
#include <hip/hip_runtime.h>
#include <math.h>

// Problem constants (from setup_inputs): N=262144, D=128, C=1024.
// R0 sorted-gather pipeline (proven 253us) with a software-pipelined
// class_sum_kernel (depth-2 row prefetch) to attack its latency-boundedness.
#define NUM_CLASSES 1024
#define HIST_CHUNK 2048            // samples per hist/scatter block
#define NB 128                     // number of hist/scatter blocks (N/HIST_CHUNK)

__device__ __forceinline__ int detect_mode32(const int* __restrict__ l) {
    // uniform scalar loads; 1 -> labels are int32, 0 -> int64 (read low words)
    return (l[1] | l[3] | l[5] | l[7] | l[9] | l[11] | l[13] | l[15]) != 0;
}

__device__ __forceinline__ int get_label(const int* __restrict__ l, int i, int mode32) {
    return l[mode32 ? i : (i << 1)] & (NUM_CLASSES - 1);
}

// ---------------- Kernel 1: per-block partial histograms (transposed out) ----------------
__global__ void hist_kernel(const int* __restrict__ labels, int n,
                            int* __restrict__ pT) {        // [C][NB]
    __shared__ int h[NUM_CLASSES];
    const int mode32 = detect_mode32(labels);
    for (int i = threadIdx.x; i < NUM_CLASSES; i += blockDim.x) h[i] = 0;
    __syncthreads();
    const int base = blockIdx.x * HIST_CHUNK;
    for (int k = threadIdx.x; k < HIST_CHUNK; k += blockDim.x) {
        int i = base + k;
        if (i < n) atomicAdd(&h[get_label(labels, i, mode32)], 1);
    }
    __syncthreads();
    for (int c = threadIdx.x; c < NUM_CLASSES; c += blockDim.x)
        pT[c * NB + blockIdx.x] = h[c];
}

// ---------------- Kernel 2a: per-class prefix along blocks (wave per class) ----------------
__global__ __launch_bounds__(512) void scanA_kernel(int* __restrict__ pT,
                                                    int* __restrict__ totals) {
    const int wave = threadIdx.x >> 6;
    const int lane = threadIdx.x & 63;
    const int c = blockIdx.x * 8 + wave;        // 128 blocks x 8 waves = 1024
    int* p = pT + c * NB;
    const int v0 = p[2 * lane];
    const int v1 = p[2 * lane + 1];
    int s = v0 + v1;
    #pragma unroll
    for (int d = 1; d < 64; d <<= 1) {
        int t = __shfl_up(s, d, 64);
        if (lane >= d) s += t;
    }
    const int base = s - v0 - v1;               // exclusive prefix before this pair
    p[2 * lane]     = base;
    p[2 * lane + 1] = base + v0;
    if (lane == 63) totals[c] = s;
}

// ---------------- Kernel 2b: cross-class exclusive scan (1 block) ----------------
__global__ void scanB_kernel(const int* __restrict__ totals,
                             int* __restrict__ offsets,
                             int* __restrict__ counts,
                             float* __restrict__ accum,
                             int* __restrict__ ticket) {
    __shared__ int tmp[NUM_CLASSES];
    const int c = threadIdx.x;                  // blockDim.x == 1024
    const int v = totals[c];
    tmp[c] = v;
    __syncthreads();
    for (int off = 1; off < NUM_CLASSES; off <<= 1) {
        int add = (c >= off) ? tmp[c - off] : 0;
        __syncthreads();
        tmp[c] += add;
        __syncthreads();
    }
    offsets[c] = tmp[c] - v;
    counts[c]  = v;
    if (c == 0) { accum[0] = 0.0f; accum[1] = 0.0f; *ticket = 0; }
}

// ---------------- Kernel 3: scatter via LDS cursors (no global atomics) ----------------
__global__ void scatter_kernel(const int* __restrict__ labels, int n,
                               const int* __restrict__ pT,
                               const int* __restrict__ offsets,
                               int* __restrict__ sorted) {
    __shared__ int cur[NUM_CLASSES];
    const int mode32 = detect_mode32(labels);
    for (int c = threadIdx.x; c < NUM_CLASSES; c += blockDim.x)
        cur[c] = offsets[c] + pT[c * NB + blockIdx.x];
    __syncthreads();
    const int base = blockIdx.x * HIST_CHUNK;
    for (int k = threadIdx.x; k < HIST_CHUNK; k += blockDim.x) {
        int i = base + k;
        if (i < n) {
            int pos = atomicAdd(&cur[get_label(labels, i, mode32)], 1);  // LDS atomic
            sorted[pos] = i;
        }
    }
}

// ---------------- Kernel 4: per-class normalized sum + loss (+finalize) ----------------
// One block (8 waves) per class. 16 lanes per row; wave handles 4 rows/iter.
// Identity: sum_{i in c} dot(emb_i, proto_c) = ||sum_{i in c} norm(emb_i)||,
// so per_class = (count - ||sum||) / count. Last block (ticket) finalizes.
// Depth-2 software pipeline: while reducing row A, row B's loads are in
// flight and index C (two iterations ahead) is being fetched. Accumulation
// order per 16-lane group is unchanged vs the depth-1 version.
#define WPB 8
__global__ __launch_bounds__(512) void class_sum_kernel(
        const float* __restrict__ emb,      // N x 128 fp32
        const int* __restrict__ sorted,
        const int* __restrict__ offsets,
        const int* __restrict__ counts,
        float* __restrict__ accum,          // [0]=loss_sum, [1]=n_valid
        int* __restrict__ ticket,
        float* __restrict__ out) {
    const int c     = blockIdx.x;
    const int start = offsets[c];
    const int count = counts[c];
    const int wave  = threadIdx.x >> 6;
    const int lane  = threadIdx.x & 63;
    const int g     = lane >> 4;            // row-group 0..3 within wave
    const int sub   = lane & 15;            // lane within row
    const int STRIDE = WPB * 4;             // 32 row-groups per block

    const float4* emb4 = (const float4*)emb;

    float4 aLo = make_float4(0.f, 0.f, 0.f, 0.f);
    float4 aHi = make_float4(0.f, 0.f, 0.f, 0.f);

    int  rA   = wave * 4 + g;
    bool vA   = rA < count;
    int  idxA = vA ? sorted[start + rA] : 0;
    float4 a0 = make_float4(0.f, 0.f, 0.f, 0.f), a1 = a0;
    if (vA) {
        const float4* p = emb4 + (size_t)idxA * 32;
        a0 = p[sub];
        a1 = p[sub + 16];
    }
    int  rB   = rA + STRIDE;
    bool vB   = rB < count;
    int  idxB = vB ? sorted[start + rB] : 0;

    while (vA) {
        // prefetch row B (in flight while A is reduced)
        float4 b0, b1;
        if (vB) {
            const float4* p = emb4 + (size_t)idxB * 32;
            b0 = p[sub];
            b1 = p[sub + 16];
        } else {
            b0 = make_float4(0.f, 0.f, 0.f, 0.f);
            b1 = b0;
        }
        // prefetch index C (two iterations ahead; L2-resident, hides idx latency)
        int  rC   = rB + STRIDE;
        bool vC   = rC < count;
        int  idxC = vC ? sorted[start + rC] : 0;

        // reduce row A
        float sq = a0.x*a0.x + a0.y*a0.y + a0.z*a0.z + a0.w*a0.w
                 + a1.x*a1.x + a1.y*a1.y + a1.z*a1.z + a1.w*a1.w;
        sq += __shfl_xor(sq, 1, 64);
        sq += __shfl_xor(sq, 2, 64);
        sq += __shfl_xor(sq, 4, 64);
        sq += __shfl_xor(sq, 8, 64);
        float inv = 1.0f / fmaxf(sqrtf(sq), 1e-12f);
        aLo.x += a0.x * inv; aLo.y += a0.y * inv; aLo.z += a0.z * inv; aLo.w += a0.w * inv;
        aHi.x += a1.x * inv; aHi.y += a1.y * inv; aHi.z += a1.z * inv; aHi.w += a1.w * inv;

        // rotate pipeline
        a0 = b0; a1 = b1;
        vA = vB; vB = vC; idxB = idxC; rB = rC;
    }

    // Reduce 32 partial vectors (8 waves x 4 groups) of 128 dims.
    __shared__ float s[WPB * 4][16][8];     // 16 KB
    {
        float* dst = s[wave * 4 + g][sub];
        dst[0] = aLo.x; dst[1] = aLo.y; dst[2] = aLo.z; dst[3] = aLo.w;
        dst[4] = aHi.x; dst[5] = aHi.y; dst[6] = aHi.z; dst[7] = aHi.w;
    }
    __syncthreads();

    __shared__ float red[128];
    if (threadIdx.x < 128) {
        const int d  = threadIdx.x;
        const int dd = d & 63;
        const int sb = dd >> 2;
        const int j  = (d >> 6) * 4 + (dd & 3);
        float t = 0.0f;
        #pragma unroll
        for (int k = 0; k < WPB * 4; k++) t += s[k][sb][j];
        red[d] = t * t;
    }
    __syncthreads();
    if (threadIdx.x < 64) {
        float x = red[threadIdx.x] + red[threadIdx.x + 64];
        #pragma unroll
        for (int off = 32; off; off >>= 1) x += __shfl_xor(x, off, 64);
        if (threadIdx.x == 0) {
            if (count >= 2) {
                float nrm = sqrtf(x);                   // = sum over class of sim
                float per_class = ((float)count - nrm) / (float)count;
                atomicAdd(&accum[0], per_class);
                atomicAdd(&accum[1], 1.0f);
            }
            __threadfence();
            int old = atomicAdd(ticket, 1);
            if (old == NUM_CLASSES - 1) {
                // device-scope atomic reads (cross-XCD safe)
                float ls = atomicAdd(&accum[0], 0.0f);
                float nv = atomicAdd(&accum[1], 0.0f);
                out[0] = (nv > 0.0f) ? (ls / nv) : 0.0f;
            }
        }
    }
}

extern "C" void kernel_launch(void* const* d_in, const int* in_sizes, int n_in,
                              void* d_out, int out_size, void* d_ws, size_t ws_size,
                              hipStream_t stream) {
    const float* emb  = (const float*)d_in[0];   // fp32, N x 128
    const int* labels = (const int*)d_in[1];     // int32 (int64 handled inline)
    const int n = in_sizes[1];                   // 262144 samples

    // Workspace layout (~1.55 MB)
    char* ws = (char*)d_ws;
    int*   counts  = (int*)(ws + 0);                       // 1024 ints
    int*   offsets = (int*)(ws + 4096);                    // 1024 ints
    int*   totals  = (int*)(ws + 8192);                    // 1024 ints
    float* accum   = (float*)(ws + 12288);                 // 2 floats
    int*   ticket  = (int*)(ws + 12304);                   // 1 int
    int*   sorted  = (int*)(ws + 16384);                   // n ints (1 MB)
    int*   pT      = (int*)(ws + 16384 + (size_t)n * 4);   // C*NB ints (512 KB)

    hist_kernel <<<NB, 256, 0, stream>>>(labels, n, pT);
    scanA_kernel<<<NB, 512, 0, stream>>>(pT, totals);
    scanB_kernel<<<1, NUM_CLASSES, 0, stream>>>(totals, offsets, counts, accum, ticket);
    scatter_kernel<<<NB, 256, 0, stream>>>(labels, n, pT, offsets, sorted);
    class_sum_kernel<<<NUM_CLASSES, 512, 0, stream>>>(emb, sorted, offsets, counts,
                                                      accum, ticket, (float*)d_out);
}